// Round 1
// baseline (91.463 us; speedup 1.0000x reference)
//
#include <hip/hip_runtime.h>
#include <hip/hip_bf16.h>
#include <cstdint>
#include <cstddef>

typedef __attribute__((ext_vector_type(8))) short bf16x8;
typedef __attribute__((ext_vector_type(4))) float f32x4;
typedef __attribute__((ext_vector_type(4))) uint32_t u32x4;

#define HW 4096
#define NB 2
#define NH 8
#define HD 8

static __device__ __forceinline__ short f2bf(float f) {
    uint32_t u = __float_as_uint(f);
    u += 0x7fffu + ((u >> 16) & 1u);   // round-to-nearest-even
    return (short)(u >> 16);
}

static __device__ __forceinline__ uint32_t cvt_pk_bf16(float lo, float hi) {
    uint32_t r;
    asm("v_cvt_pk_bf16_f32 %0, %1, %2" : "=v"(r) : "v"(lo), "v"(hi));
    return r;
}

// ---------------------------------------------------------------------------
// Merged projection kernel. W staged TRANSPOSED in LDS with +4 pad so each
// lane reads its own output-column row via ds_read_b128.
// blocks [0,1024):   q = x@Wq+bq, L2-norm/head, pre-scaled temp*log2e -> Qb
// blocks [1024,2048): kv = y@Wkv+bkv; k L2-normed -> Kb; V -> VTp (permuted
//                     transpose, row 8 = ones for the denominator).
// ---------------------------------------------------------------------------
__global__ __launch_bounds__(256) void proj_kernel(
    const float* __restrict__ x, const float* __restrict__ y,
    const float* __restrict__ Wq, const float* __restrict__ bq,
    const float* __restrict__ Wkv, const float* __restrict__ bkv,
    const float* __restrict__ temp,
    short* __restrict__ Qb, short* __restrict__ Kb, short* __restrict__ VTp)
{
    __shared__ float wT[128 * 68];   // 34.8 KB; q path uses rows 0..63
    __shared__ float rr[4][64];

    const int nqblk = (NB * HW) / 8;   // 1024
    const int rl = threadIdx.x >> 6;
    const int c  = threadIdx.x & 63;

    if ((int)blockIdx.x < nqblk) {
        for (int idx = threadIdx.x; idx < 64 * 64; idx += 256)
            wT[(idx & 63) * 68 + (idx >> 6)] = Wq[idx];
        __syncthreads();

        const float biq = bq[c];
        const int hh = c >> 3, d = c & 7;
        const float tl = temp[hh] * 1.44269504f;   // fold temp*log2(e) into Q
        const int row0 = blockIdx.x * 8;

        #pragma unroll
        for (int rg = 0; rg < 2; ++rg) {
            const int row = row0 + rg * 4 + rl;
            rr[rl][c] = x[(size_t)row * 64 + c];   // wave-synchronous broadcast

            float aq = biq;
            #pragma unroll
            for (int q4 = 0; q4 < 16; ++q4) {
                const float4 wv = *(const float4*)&wT[c * 68 + q4 * 4];
                const float4 xv = *(const float4*)&rr[rl][q4 * 4];
                aq = fmaf(xv.x, wv.x, aq);
                aq = fmaf(xv.y, wv.y, aq);
                aq = fmaf(xv.z, wv.z, aq);
                aq = fmaf(xv.w, wv.w, aq);
            }
            float nq = aq * aq;
            nq += __shfl_xor(nq, 1); nq += __shfl_xor(nq, 2); nq += __shfl_xor(nq, 4);
            const float qn = aq / fmaxf(sqrtf(nq), 1e-12f);

            const int b = row >> 12;
            const int i = row & (HW - 1);
            Qb[(((size_t)(b * NH + hh)) * HW + i) * HD + d] = f2bf(qn * tl);
        }
    } else {
        for (int idx = threadIdx.x; idx < 64 * 128; idx += 256)
            wT[(idx & 127) * 68 + (idx >> 7)] = Wkv[idx];
        __syncthreads();

        const float bik = bkv[c];
        const float biv = bkv[c + 64];
        const int row0 = ((int)blockIdx.x - nqblk) * 8;

        #pragma unroll
        for (int rg = 0; rg < 2; ++rg) {
            const int row = row0 + rg * 4 + rl;
            rr[rl][c] = y[(size_t)row * 64 + c];

            float ak = bik, av = biv;
            #pragma unroll
            for (int q4 = 0; q4 < 16; ++q4) {
                const float4 wk = *(const float4*)&wT[c * 68 + q4 * 4];
                const float4 wv4 = *(const float4*)&wT[(c + 64) * 68 + q4 * 4];
                const float4 yv = *(const float4*)&rr[rl][q4 * 4];
                ak = fmaf(yv.x, wk.x, ak);
                ak = fmaf(yv.y, wk.y, ak);
                ak = fmaf(yv.z, wk.z, ak);
                ak = fmaf(yv.w, wk.w, ak);
                av = fmaf(yv.x, wv4.x, av);
                av = fmaf(yv.y, wv4.y, av);
                av = fmaf(yv.z, wv4.z, av);
                av = fmaf(yv.w, wv4.w, av);
            }
            float nk = ak * ak;
            nk += __shfl_xor(nk, 1); nk += __shfl_xor(nk, 2); nk += __shfl_xor(nk, 4);
            const float kn = ak / fmaxf(sqrtf(nk), 1e-12f);

            const int b = row >> 12;
            const int i = row & (HW - 1);
            const int hh = c >> 3, d = c & 7;
            const int bh = b * NH + hh;
            Kb[(((size_t)bh) * HW + i) * HD + d] = f2bf(kn);

            // permuted-transposed V store: slot s=g*8+e holds j = g*4+e (e<4)
            // or 16+g*4+(e-4); store via inverse permutation.
            const int jj = i & 31;
            const int slot = (jj < 16) ? ((jj >> 2) * 8 + (jj & 3))
                                       : (((jj & 15) >> 2) * 8 + 4 + (jj & 3));
            VTp[((size_t)(bh * 9 + d)) * HW + (i & ~31) + slot] = f2bf(av);
            if (d == 0)
                VTp[((size_t)(bh * 9 + 8)) * HW + i] = (short)0x3F80;  // ones
        }
    }
}

// ---------------------------------------------------------------------------
// Attention: 512-thr blocks = 8 waves = 4 i-tiles x 2 j-halves.
// K is consumed DIRECTLY from global (L1/L2-resident) in MFMA fragment form:
// since qf==0 for lanes g>0, only A columns 0..7 matter in the S-MFMA, so
// lane l's K fragment is just the contiguous 16B row slice at row (.. + il).
// This deletes the former per-wave LDS staging round trip (4x ds_read_b128 +
// 1x ds_write_b128 per 64-j chunk = 1.3 GB of LDS traffic kernel-wide) and
// its ordering hazards. Register prefetch 1 step (32 j) deep; per-step wall
// time at 8 waves/SIMD (~1K cyc) dwarfs L2 latency, so loads fully hide.
// Per step (32 j):  S' = mfma(K, Q');  p = exp2(S');  pack -> bf16x8;
//                   acc = mfma(V_perm, P, acc)   (V: 1-step reg prefetch)
// j-halves combined via LDS; denominator = V ones-row (d-row 8).
// ---------------------------------------------------------------------------
__global__ __launch_bounds__(512, 4) void attn_kernel(
    const short* __restrict__ Qb, const short* __restrict__ Kb,
    const short* __restrict__ VTp, float* __restrict__ out)
{
    __shared__ f32x4 red[8][64];          // 8 KB (epilogue reduction only)

    const int blk  = blockIdx.x;       // 1024 = 16 bh * 64 itile-groups
    const int bh   = blk >> 6;
    const int h    = bh & (NH - 1);
    const int b    = bh >> 3;
    const int lane = threadIdx.x & 63;
    const int wave = threadIdx.x >> 6; // 0..7
    const int iw   = wave & 3;         // i-sub-tile
    const int jh   = wave >> 2;        // j-half
    const int il   = lane & 15;
    const int g    = lane >> 4;
    const int i    = (blk & 63) * 64 + iw * 16 + il;

    bf16x8 qf = {0, 0, 0, 0, 0, 0, 0, 0};
    if (g == 0)
        qf = *(const bf16x8*)(Qb + ((size_t)bh * HW + i) * HD);

    const int j0 = jh * (HW / 2);
    // lane-l K fragment base: row (j0 + il), 16B contiguous (dims 0..7).
    // Lanes g=0..3 share an address -> coalescer broadcast.
    const short* kbl = Kb + ((size_t)bh * HW + j0 + il) * HD;
    const int vrow = (il <= 8) ? il : 8;
    const short* vpl = VTp + ((size_t)(bh * 9 + vrow)) * HW + j0 + g * 8;

    f32x4 acc = {0.f, 0.f, 0.f, 0.f};

    auto step = [&](const bf16x8 ka, const bf16x8 kb2, const bf16x8 vcur) {
        const f32x4 z = {0.f, 0.f, 0.f, 0.f};
        const f32x4 s0 = __builtin_amdgcn_mfma_f32_16x16x32_bf16(ka,  qf, z, 0, 0, 0);
        const f32x4 s1 = __builtin_amdgcn_mfma_f32_16x16x32_bf16(kb2, qf, z, 0, 0, 0);
        const float p0 = __builtin_amdgcn_exp2f(s0[0]);
        const float p1 = __builtin_amdgcn_exp2f(s0[1]);
        const float p2 = __builtin_amdgcn_exp2f(s0[2]);
        const float p3 = __builtin_amdgcn_exp2f(s0[3]);
        const float p4 = __builtin_amdgcn_exp2f(s1[0]);
        const float p5 = __builtin_amdgcn_exp2f(s1[1]);
        const float p6 = __builtin_amdgcn_exp2f(s1[2]);
        const float p7 = __builtin_amdgcn_exp2f(s1[3]);
        union { u32x4 u; bf16x8 v; } pu;
        pu.u = (u32x4){ cvt_pk_bf16(p0, p1), cvt_pk_bf16(p2, p3),
                        cvt_pk_bf16(p4, p5), cvt_pk_bf16(p6, p7) };
        acc = __builtin_amdgcn_mfma_f32_16x16x32_bf16(vcur, pu.v, acc, 0, 0, 0);
    };

    // prologue: load step-0 fragments (2x K 16B, 1x V 16B)
    bf16x8 k0 = *(const bf16x8*)(kbl);
    bf16x8 k1 = *(const bf16x8*)(kbl + 16 * HD);
    bf16x8 vv = *(const bf16x8*)(vpl);

    // 64 steps of 32 j each; prefetch next step's fragments before computing
    for (int u = 0; u < 63; ++u) {
        const short* kn = kbl + (size_t)(u + 1) * 32 * HD;
        const bf16x8 nk0 = *(const bf16x8*)(kn);
        const bf16x8 nk1 = *(const bf16x8*)(kn + 16 * HD);
        const bf16x8 nv  = *(const bf16x8*)(vpl + (size_t)(u + 1) * 32);
        __builtin_amdgcn_sched_barrier(0);   // keep loads above the compute

        step(k0, k1, vv);

        k0 = nk0; k1 = nk1; vv = nv;
    }
    // epilogue step (no prefetch)
    step(k0, k1, vv);

    // combine the two j-halves (waves w and w+4) via LDS
    red[wave][lane] = acc;
    __syncthreads();
    if (wave < 4) {
        const f32x4 other = red[wave + 4][lane];
        acc[0] += other[0]; acc[1] += other[1];
        acc[2] += other[2]; acc[3] += other[3];
        // denominator sits in d-row 8 = (g=2, reg 0), same column i
        const float den = __shfl(acc[0], il + 32);
        if (g < 2) {
            const float inv = 1.0f / den;
            float4 o;
            o.x = acc[0] * inv;
            o.y = acc[1] * inv;
            o.z = acc[2] * inv;
            o.w = acc[3] * inv;
            *(float4*)(out + ((size_t)b * HW + i) * 64 + h * 8 + g * 4) = o;
        }
    }
}

extern "C" void kernel_launch(void* const* d_in, const int* in_sizes, int n_in,
                              void* d_out, int out_size, void* d_ws, size_t ws_size,
                              hipStream_t stream) {
    const float* x    = (const float*)d_in[0];
    const float* y    = (const float*)d_in[1];
    const float* Wq   = (const float*)d_in[2];
    const float* bq   = (const float*)d_in[3];
    const float* Wkv  = (const float*)d_in[4];
    const float* bkv  = (const float*)d_in[5];
    const float* temp = (const float*)d_in[6];
    float* out = (float*)d_out;

    const size_t NQK = (size_t)NB * NH * HW * HD;   // 524288
    short* Qb  = (short*)d_ws;                       // 1 MB
    short* Kb  = Qb + NQK;                           // 1 MB
    short* VTp = Kb + NQK;                           // 1.125 MB

    proj_kernel<<<2 * (NB * HW) / 8, 256, 0, stream>>>(x, y, Wq, bq, Wkv, bkv,
                                                       temp, Qb, Kb, VTp);
    attn_kernel<<<NB * NH * (HW / 64), 512, 0, stream>>>(Qb, Kb, VTp, out);
}

// Round 5
// 69.048 us; speedup vs baseline: 1.3246x; 1.3246x over previous
//
#include <hip/hip_runtime.h>
#include <hip/hip_bf16.h>
#include <cstdint>
#include <cstddef>

typedef __attribute__((ext_vector_type(8))) short bf16x8;
typedef __attribute__((ext_vector_type(4))) float f32x4;
typedef __attribute__((ext_vector_type(4))) uint32_t u32x4;

#define HW 4096
#define NB 2
#define NH 8
#define HD 8

static __device__ __forceinline__ short f2bf(float f) {
    uint32_t u = __float_as_uint(f);
    u += 0x7fffu + ((u >> 16) & 1u);   // round-to-nearest-even
    return (short)(u >> 16);
}

static __device__ __forceinline__ uint32_t cvt_pk_bf16(float lo, float hi) {
    uint32_t r;
    asm("v_cvt_pk_bf16_f32 %0, %1, %2" : "=v"(r) : "v"(lo), "v"(hi));
    return r;
}

// ---------------------------------------------------------------------------
// Merged projection kernel. W staged TRANSPOSED in LDS with +4 pad so each
// lane reads its own output-column row via ds_read_b128.
// Round-5 change: 16 rows per block (was 8) -> half the blocks, so the
// per-block W staging (the dominant fixed cost: 16-32KB re-load + 8-way
// conflicted transpose scatter) is amortized over 2x the output rows.
// Per-row compute body is untouched.
// blocks [0,512):    q = x@Wq+bq, L2-norm/head, pre-scaled temp*log2e -> Qb
// blocks [512,1024): kv = y@Wkv+bkv; k L2-normed -> Kb; V -> VTp (permuted
//                    transpose, row 8 = ones for the denominator).
// ---------------------------------------------------------------------------
__global__ __launch_bounds__(256) void proj_kernel(
    const float* __restrict__ x, const float* __restrict__ y,
    const float* __restrict__ Wq, const float* __restrict__ bq,
    const float* __restrict__ Wkv, const float* __restrict__ bkv,
    const float* __restrict__ temp,
    short* __restrict__ Qb, short* __restrict__ Kb, short* __restrict__ VTp)
{
    __shared__ float wT[128 * 68];   // 34.8 KB; q path uses rows 0..63
    __shared__ float rr[4][64];

    const int nqblk = (NB * HW) / 16;   // 512
    const int rl = threadIdx.x >> 6;
    const int c  = threadIdx.x & 63;

    if ((int)blockIdx.x < nqblk) {
        for (int idx = threadIdx.x; idx < 64 * 64; idx += 256)
            wT[(idx & 63) * 68 + (idx >> 6)] = Wq[idx];
        __syncthreads();

        const float biq = bq[c];
        const int hh = c >> 3, d = c & 7;
        const float tl = temp[hh] * 1.44269504f;   // fold temp*log2(e) into Q
        const int row0 = blockIdx.x * 16;

        #pragma unroll
        for (int rg = 0; rg < 4; ++rg) {
            const int row = row0 + rg * 4 + rl;
            rr[rl][c] = x[(size_t)row * 64 + c];   // wave-synchronous broadcast

            float aq = biq;
            #pragma unroll
            for (int q4 = 0; q4 < 16; ++q4) {
                const float4 wv = *(const float4*)&wT[c * 68 + q4 * 4];
                const float4 xv = *(const float4*)&rr[rl][q4 * 4];
                aq = fmaf(xv.x, wv.x, aq);
                aq = fmaf(xv.y, wv.y, aq);
                aq = fmaf(xv.z, wv.z, aq);
                aq = fmaf(xv.w, wv.w, aq);
            }
            float nq = aq * aq;
            nq += __shfl_xor(nq, 1); nq += __shfl_xor(nq, 2); nq += __shfl_xor(nq, 4);
            const float qn = aq / fmaxf(sqrtf(nq), 1e-12f);

            const int b = row >> 12;
            const int i = row & (HW - 1);
            Qb[(((size_t)(b * NH + hh)) * HW + i) * HD + d] = f2bf(qn * tl);
        }
    } else {
        for (int idx = threadIdx.x; idx < 64 * 128; idx += 256)
            wT[(idx & 127) * 68 + (idx >> 7)] = Wkv[idx];
        __syncthreads();

        const float bik = bkv[c];
        const float biv = bkv[c + 64];
        const int row0 = ((int)blockIdx.x - nqblk) * 16;

        #pragma unroll
        for (int rg = 0; rg < 4; ++rg) {
            const int row = row0 + rg * 4 + rl;
            rr[rl][c] = y[(size_t)row * 64 + c];

            float ak = bik, av = biv;
            #pragma unroll
            for (int q4 = 0; q4 < 16; ++q4) {
                const float4 wk = *(const float4*)&wT[c * 68 + q4 * 4];
                const float4 wv4 = *(const float4*)&wT[(c + 64) * 68 + q4 * 4];
                const float4 yv = *(const float4*)&rr[rl][q4 * 4];
                ak = fmaf(yv.x, wk.x, ak);
                ak = fmaf(yv.y, wk.y, ak);
                ak = fmaf(yv.z, wk.z, ak);
                ak = fmaf(yv.w, wk.w, ak);
                av = fmaf(yv.x, wv4.x, av);
                av = fmaf(yv.y, wv4.y, av);
                av = fmaf(yv.z, wv4.z, av);
                av = fmaf(yv.w, wv4.w, av);
            }
            float nk = ak * ak;
            nk += __shfl_xor(nk, 1); nk += __shfl_xor(nk, 2); nk += __shfl_xor(nk, 4);
            const float kn = ak / fmaxf(sqrtf(nk), 1e-12f);

            const int b = row >> 12;
            const int i = row & (HW - 1);
            const int hh = c >> 3, d = c & 7;
            const int bh = b * NH + hh;
            Kb[(((size_t)bh) * HW + i) * HD + d] = f2bf(kn);

            // permuted-transposed V store: slot s=g*8+e holds j = g*4+e (e<4)
            // or 16+g*4+(e-4); store via inverse permutation.
            const int jj = i & 31;
            const int slot = (jj < 16) ? ((jj >> 2) * 8 + (jj & 3))
                                       : (((jj & 15) >> 2) * 8 + 4 + (jj & 3));
            VTp[((size_t)(bh * 9 + d)) * HW + (i & ~31) + slot] = f2bf(av);
            if (d == 0)
                VTp[((size_t)(bh * 9 + 8)) * HW + i] = (short)0x3F80;  // ones
        }
    }
}

// ---------------------------------------------------------------------------
// Attention: 512-thr blocks = 8 waves = 4 i-tiles x 2 j-halves.
// Per-wave PRIVATE K staging (no cross-wave LDS dependencies, no barriers in
// the main loop): each wave's lane l stages row (chunk*64 + l) of its j-half
// into its own double-buffered 2 KB LDS region via global->reg->ds_write.
// The global load for chunk t+1 is issued before the compute of chunk t
// (pinned by sched_barrier) and consumed only at the trailing ds_write, so
// its latency hides under ~2 steps of MFMA/exp work. RAW between the ds_write
// and next-iteration ds_reads is same-wave LDS in-order execution.
// NOTE: this loop is schedule-fragile (rounds 2-4: any body perturbation
// fails verification). Kept BYTE-IDENTICAL to the round-0 verified source.
// Per step (32 j):  S' = mfma(K_lds, Q');  p = exp2(S');  pack -> bf16x8;
//                   acc = mfma(V_perm, P, acc)   (V: 2-deep reg prefetch)
// j-halves combined via LDS; denominator = V ones-row (d-row 8).
// ---------------------------------------------------------------------------
__global__ __launch_bounds__(512, 4) void attn_kernel(
    const short* __restrict__ Qb, const short* __restrict__ Kb,
    const short* __restrict__ VTp, float* __restrict__ out)
{
    __shared__ short Kl[8][2][64 * HD];   // 16 KB: per-wave private dbuf
    __shared__ f32x4 red[8][64];          // 8 KB

    const int blk  = blockIdx.x;       // 1024 = 16 bh * 64 itile-groups
    const int bh   = blk >> 6;
    const int h    = bh & (NH - 1);
    const int b    = bh >> 3;
    const int lane = threadIdx.x & 63;
    const int wave = threadIdx.x >> 6; // 0..7
    const int iw   = wave & 3;         // i-sub-tile
    const int jh   = wave >> 2;        // j-half
    const int il   = lane & 15;
    const int g    = lane >> 4;
    const int i    = (blk & 63) * 64 + iw * 16 + il;

    bf16x8 qf = {0, 0, 0, 0, 0, 0, 0, 0};
    if (g == 0)
        qf = *(const bf16x8*)(Qb + ((size_t)bh * HW + i) * HD);

    const int j0 = jh * (HW / 2);
    const short* ksrc = Kb + ((size_t)bh * HW + j0 + lane) * HD;  // + t*64*HD
    const int vrow = (il <= 8) ? il : 8;
    const short* vptr = VTp + ((size_t)(bh * 9 + vrow)) * HW + j0 + g * 8;

    f32x4 acc = {0.f, 0.f, 0.f, 0.f};

    auto step = [&](const short* kl, const bf16x8 vcur, const int s) {
        const bf16x8 k0 = *(const bf16x8*)&kl[(s * 32 + il) * HD];
        const bf16x8 k1 = *(const bf16x8*)&kl[(s * 32 + 16 + il) * HD];
        const f32x4 z = {0.f, 0.f, 0.f, 0.f};
        const f32x4 s0 = __builtin_amdgcn_mfma_f32_16x16x32_bf16(k0, qf, z, 0, 0, 0);
        const f32x4 s1 = __builtin_amdgcn_mfma_f32_16x16x32_bf16(k1, qf, z, 0, 0, 0);
        const float p0 = __builtin_amdgcn_exp2f(s0[0]);
        const float p1 = __builtin_amdgcn_exp2f(s0[1]);
        const float p2 = __builtin_amdgcn_exp2f(s0[2]);
        const float p3 = __builtin_amdgcn_exp2f(s0[3]);
        const float p4 = __builtin_amdgcn_exp2f(s1[0]);
        const float p5 = __builtin_amdgcn_exp2f(s1[1]);
        const float p6 = __builtin_amdgcn_exp2f(s1[2]);
        const float p7 = __builtin_amdgcn_exp2f(s1[3]);
        union { u32x4 u; bf16x8 v; } pu;
        pu.u = (u32x4){ cvt_pk_bf16(p0, p1), cvt_pk_bf16(p2, p3),
                        cvt_pk_bf16(p4, p5), cvt_pk_bf16(p6, p7) };
        acc = __builtin_amdgcn_mfma_f32_16x16x32_bf16(vcur, pu.v, acc, 0, 0, 0);
    };

    // prologue: stage chunk 0 (own-wave synchronous), prefetch V 2 deep
    bf16x8 kreg = *(const bf16x8*)(ksrc);
    bf16x8 vvA  = *(const bf16x8*)(vptr);
    bf16x8 vvB  = *(const bf16x8*)(vptr + 32);
    *(bf16x8*)&Kl[wave][0][lane * HD] = kreg;

    int buf = 0;
    for (int t = 0; t < 31; ++t) {
        // issue next chunk's loads early; consumed only at the trailing write
        const bf16x8 knext = *(const bf16x8*)(ksrc + (size_t)(t + 1) * 64 * HD);
        const bf16x8 vA2   = *(const bf16x8*)(vptr + (size_t)(2 * t + 2) * 32);
        const bf16x8 vB2   = *(const bf16x8*)(vptr + (size_t)(2 * t + 3) * 32);
        __builtin_amdgcn_sched_barrier(0);   // keep loads above the compute

        const short* kl = &Kl[wave][buf][0];
        step(kl, vvA, 0);
        step(kl, vvB, 1);

        *(bf16x8*)&Kl[wave][buf ^ 1][lane * HD] = knext;
        vvA = vA2;
        vvB = vB2;
        buf ^= 1;
    }
    // epilogue chunk (no prefetch)
    {
        const short* kl = &Kl[wave][buf][0];
        step(kl, vvA, 0);
        step(kl, vvB, 1);
    }

    // combine the two j-halves (waves w and w+4) via LDS
    red[wave][lane] = acc;
    __syncthreads();
    if (wave < 4) {
        const f32x4 other = red[wave + 4][lane];
        acc[0] += other[0]; acc[1] += other[1];
        acc[2] += other[2]; acc[3] += other[3];
        // denominator sits in d-row 8 = (g=2, reg 0), same column i
        const float den = __shfl(acc[0], il + 32);
        if (g < 2) {
            const float inv = 1.0f / den;
            float4 o;
            o.x = acc[0] * inv;
            o.y = acc[1] * inv;
            o.z = acc[2] * inv;
            o.w = acc[3] * inv;
            *(float4*)(out + ((size_t)b * HW + i) * 64 + h * 8 + g * 4) = o;
        }
    }
}

extern "C" void kernel_launch(void* const* d_in, const int* in_sizes, int n_in,
                              void* d_out, int out_size, void* d_ws, size_t ws_size,
                              hipStream_t stream) {
    const float* x    = (const float*)d_in[0];
    const float* y    = (const float*)d_in[1];
    const float* Wq   = (const float*)d_in[2];
    const float* bq   = (const float*)d_in[3];
    const float* Wkv  = (const float*)d_in[4];
    const float* bkv  = (const float*)d_in[5];
    const float* temp = (const float*)d_in[6];
    float* out = (float*)d_out;

    const size_t NQK = (size_t)NB * NH * HW * HD;   // 524288
    short* Qb  = (short*)d_ws;                       // 1 MB
    short* Kb  = Qb + NQK;                           // 1 MB
    short* VTp = Kb + NQK;                           // 1.125 MB

    proj_kernel<<<2 * (NB * HW) / 16, 256, 0, stream>>>(x, y, Wq, bq, Wkv, bkv,
                                                        temp, Qb, Kb, VTp);
    attn_kernel<<<NB * NH * (HW / 64), 512, 0, stream>>>(Qb, Kb, VTp, out);
}

// Round 7
// 63.908 us; speedup vs baseline: 1.4312x; 1.0804x over previous
//
#include <hip/hip_runtime.h>
#include <hip/hip_bf16.h>
#include <cstdint>
#include <cstddef>

typedef __attribute__((ext_vector_type(8))) short bf16x8;
typedef __attribute__((ext_vector_type(4))) float f32x4;
typedef __attribute__((ext_vector_type(4))) uint32_t u32x4;

#define HW 4096
#define NB 2
#define NH 8
#define HD 8

static __device__ __forceinline__ short f2bf(float f) {
    uint32_t u = __float_as_uint(f);
    u += 0x7fffu + ((u >> 16) & 1u);   // round-to-nearest-even
    return (short)(u >> 16);
}

static __device__ __forceinline__ uint32_t cvt_pk_bf16(float lo, float hi) {
    uint32_t r;
    asm("v_cvt_pk_bf16_f32 %0, %1, %2" : "=v"(r) : "v"(lo), "v"(hi));
    return r;
}

// ---------------------------------------------------------------------------
// Merged projection kernel (verified round-5 form: 16 rows/block).
// blocks [0,512):    q = x@Wq+bq, L2-norm/head, pre-scaled temp*log2e -> Qb
// blocks [512,1024): kv = y@Wkv+bkv; k L2-normed -> Kb; V -> VTp (permuted
//                    transpose, row 8 = ones for the denominator).
// ---------------------------------------------------------------------------
__global__ __launch_bounds__(256) void proj_kernel(
    const float* __restrict__ x, const float* __restrict__ y,
    const float* __restrict__ Wq, const float* __restrict__ bq,
    const float* __restrict__ Wkv, const float* __restrict__ bkv,
    const float* __restrict__ temp,
    short* __restrict__ Qb, short* __restrict__ Kb, short* __restrict__ VTp)
{
    __shared__ float wT[128 * 68];   // 34.8 KB; q path uses rows 0..63
    __shared__ float rr[4][64];

    const int nqblk = (NB * HW) / 16;   // 512
    const int rl = threadIdx.x >> 6;
    const int c  = threadIdx.x & 63;

    if ((int)blockIdx.x < nqblk) {
        for (int idx = threadIdx.x; idx < 64 * 64; idx += 256)
            wT[(idx & 63) * 68 + (idx >> 6)] = Wq[idx];
        __syncthreads();

        const float biq = bq[c];
        const int hh = c >> 3, d = c & 7;
        const float tl = temp[hh] * 1.44269504f;   // fold temp*log2(e) into Q
        const int row0 = blockIdx.x * 16;

        #pragma unroll
        for (int rg = 0; rg < 4; ++rg) {
            const int row = row0 + rg * 4 + rl;
            rr[rl][c] = x[(size_t)row * 64 + c];   // wave-synchronous broadcast

            float aq = biq;
            #pragma unroll
            for (int q4 = 0; q4 < 16; ++q4) {
                const float4 wv = *(const float4*)&wT[c * 68 + q4 * 4];
                const float4 xv = *(const float4*)&rr[rl][q4 * 4];
                aq = fmaf(xv.x, wv.x, aq);
                aq = fmaf(xv.y, wv.y, aq);
                aq = fmaf(xv.z, wv.z, aq);
                aq = fmaf(xv.w, wv.w, aq);
            }
            float nq = aq * aq;
            nq += __shfl_xor(nq, 1); nq += __shfl_xor(nq, 2); nq += __shfl_xor(nq, 4);
            const float qn = aq / fmaxf(sqrtf(nq), 1e-12f);

            const int b = row >> 12;
            const int i = row & (HW - 1);
            Qb[(((size_t)(b * NH + hh)) * HW + i) * HD + d] = f2bf(qn * tl);
        }
    } else {
        for (int idx = threadIdx.x; idx < 64 * 128; idx += 256)
            wT[(idx & 127) * 68 + (idx >> 7)] = Wkv[idx];
        __syncthreads();

        const float bik = bkv[c];
        const float biv = bkv[c + 64];
        const int row0 = ((int)blockIdx.x - nqblk) * 16;

        #pragma unroll
        for (int rg = 0; rg < 4; ++rg) {
            const int row = row0 + rg * 4 + rl;
            rr[rl][c] = y[(size_t)row * 64 + c];

            float ak = bik, av = biv;
            #pragma unroll
            for (int q4 = 0; q4 < 16; ++q4) {
                const float4 wk = *(const float4*)&wT[c * 68 + q4 * 4];
                const float4 wv4 = *(const float4*)&wT[(c + 64) * 68 + q4 * 4];
                const float4 yv = *(const float4*)&rr[rl][q4 * 4];
                ak = fmaf(yv.x, wk.x, ak);
                ak = fmaf(yv.y, wk.y, ak);
                ak = fmaf(yv.z, wk.z, ak);
                ak = fmaf(yv.w, wk.w, ak);
                av = fmaf(yv.x, wv4.x, av);
                av = fmaf(yv.y, wv4.y, av);
                av = fmaf(yv.z, wv4.z, av);
                av = fmaf(yv.w, wv4.w, av);
            }
            float nk = ak * ak;
            nk += __shfl_xor(nk, 1); nk += __shfl_xor(nk, 2); nk += __shfl_xor(nk, 4);
            const float kn = ak / fmaxf(sqrtf(nk), 1e-12f);

            const int b = row >> 12;
            const int i = row & (HW - 1);
            const int hh = c >> 3, d = c & 7;
            const int bh = b * NH + hh;
            Kb[(((size_t)bh) * HW + i) * HD + d] = f2bf(kn);

            // permuted-transposed V store: slot s=g*8+e holds j = g*4+e (e<4)
            // or 16+g*4+(e-4); store via inverse permutation.
            const int jj = i & 31;
            const int slot = (jj < 16) ? ((jj >> 2) * 8 + (jj & 3))
                                       : (((jj & 15) >> 2) * 8 + 4 + (jj & 3));
            VTp[((size_t)(bh * 9 + d)) * HW + (i & ~31) + slot] = f2bf(av);
            if (d == 0)
                VTp[((size_t)(bh * 9 + 8)) * HW + i] = (short)0x3F80;  // ones
        }
    }
}

// ---------------------------------------------------------------------------
// Attention: 512-thr blocks = 8 waves = 4 i-tiles x 2 j-halves.
// Round-7: shared K staging in MAXIMALLY CANONICAL form. Wave iw==0 of each
// j-half stages the full 64-row chunk (lane = row, the exact r0 staging
// access pattern, full-wave, wave-UNIFORM branch -> no EXEC divergence).
// Clean 2D double-buffer indexing Ksh[(t+1)&1] / Ksh[t&1]; NO sched_barrier.
// Protocol per chunk t: read buf[t&1]; staging waves write buf[(t+1)&1];
// one __syncthreads. Write->read of buf[(t+1)&1] is gated by barrier(t);
// write-after-read (reads of that buffer at t-1) is gated by barrier(t-1).
// Chunk 31 is staged at t=30 and consumed in the epilogue.
// K global loads and K LDS writes drop 4x vs the private-staging r0 form.
// step(), V register-prefetch rotation, Q fragments, and the j-half
// reduction epilogue are VERBATIM round-0.
// Per step (32 j):  S' = mfma(K_lds, Q');  p = exp2(S');  pack -> bf16x8;
//                   acc = mfma(V_perm, P, acc)
// j-halves combined via LDS; denominator = V ones-row (d-row 8).
// ---------------------------------------------------------------------------
__global__ __launch_bounds__(512, 4) void attn_kernel(
    const short* __restrict__ Qb, const short* __restrict__ Kb,
    const short* __restrict__ VTp, float* __restrict__ out)
{
    __shared__ short Ksh[2][128 * HD];    // 4 KB: shared K dbuf (64 rows/jh)
    __shared__ f32x4 red[8][64];          // 8 KB

    const int blk  = blockIdx.x;       // 1024 = 16 bh * 64 itile-groups
    const int bh   = blk >> 6;
    const int h    = bh & (NH - 1);
    const int b    = bh >> 3;
    const int lane = threadIdx.x & 63;
    const int wave = threadIdx.x >> 6; // 0..7
    const int iw   = wave & 3;         // i-sub-tile
    const int jh   = wave >> 2;        // j-half
    const int il   = lane & 15;
    const int g    = lane >> 4;
    const int i    = (blk & 63) * 64 + iw * 16 + il;

    bf16x8 qf = {0, 0, 0, 0, 0, 0, 0, 0};
    if (g == 0)
        qf = *(const bf16x8*)(Qb + ((size_t)bh * HW + i) * HD);

    const int j0 = jh * (HW / 2);
    // staging source (only wave iw==0 of each j-half uses it): lane = row
    const short* ksrc = Kb + ((size_t)bh * HW + j0 + lane) * HD;  // + t*64*HD
    const int vrow = (il <= 8) ? il : 8;
    const short* vptr = VTp + ((size_t)(bh * 9 + vrow)) * HW + j0 + g * 8;

    f32x4 acc = {0.f, 0.f, 0.f, 0.f};

    auto step = [&](const short* kl, const bf16x8 vcur, const int s) {
        const bf16x8 k0 = *(const bf16x8*)&kl[(s * 32 + il) * HD];
        const bf16x8 k1 = *(const bf16x8*)&kl[(s * 32 + 16 + il) * HD];
        const f32x4 z = {0.f, 0.f, 0.f, 0.f};
        const f32x4 s0 = __builtin_amdgcn_mfma_f32_16x16x32_bf16(k0, qf, z, 0, 0, 0);
        const f32x4 s1 = __builtin_amdgcn_mfma_f32_16x16x32_bf16(k1, qf, z, 0, 0, 0);
        const float p0 = __builtin_amdgcn_exp2f(s0[0]);
        const float p1 = __builtin_amdgcn_exp2f(s0[1]);
        const float p2 = __builtin_amdgcn_exp2f(s0[2]);
        const float p3 = __builtin_amdgcn_exp2f(s0[3]);
        const float p4 = __builtin_amdgcn_exp2f(s1[0]);
        const float p5 = __builtin_amdgcn_exp2f(s1[1]);
        const float p6 = __builtin_amdgcn_exp2f(s1[2]);
        const float p7 = __builtin_amdgcn_exp2f(s1[3]);
        union { u32x4 u; bf16x8 v; } pu;
        pu.u = (u32x4){ cvt_pk_bf16(p0, p1), cvt_pk_bf16(p2, p3),
                        cvt_pk_bf16(p4, p5), cvt_pk_bf16(p6, p7) };
        acc = __builtin_amdgcn_mfma_f32_16x16x32_bf16(vcur, pu.v, acc, 0, 0, 0);
    };

    // prologue: staging waves stage chunk 0 into buf0; V prefetch 2 deep
    if (iw == 0)
        *(bf16x8*)&Ksh[0][(jh * 64 + lane) * HD] = *(const bf16x8*)(ksrc);
    bf16x8 vvA = *(const bf16x8*)(vptr);
    bf16x8 vvB = *(const bf16x8*)(vptr + 32);
    __syncthreads();

    for (int t = 0; t < 31; ++t) {
        bf16x8 knext;
        if (iw == 0)
            knext = *(const bf16x8*)(ksrc + (size_t)(t + 1) * 64 * HD);
        const bf16x8 vA2 = *(const bf16x8*)(vptr + (size_t)(2 * t + 2) * 32);
        const bf16x8 vB2 = *(const bf16x8*)(vptr + (size_t)(2 * t + 3) * 32);

        const short* kl = &Ksh[t & 1][jh * 64 * HD];
        step(kl, vvA, 0);
        step(kl, vvB, 1);

        if (iw == 0)
            *(bf16x8*)&Ksh[(t + 1) & 1][(jh * 64 + lane) * HD] = knext;
        vvA = vA2;
        vvB = vB2;
        __syncthreads();   // publish buf[(t+1)&1]; retire reads of buf[t&1]
    }
    // epilogue: chunk 31 (staged at t=30 into buf1, published by its barrier)
    {
        const short* kl = &Ksh[1][jh * 64 * HD];
        step(kl, vvA, 0);
        step(kl, vvB, 1);
    }

    // combine the two j-halves (waves w and w+4) via LDS
    red[wave][lane] = acc;
    __syncthreads();
    if (wave < 4) {
        const f32x4 other = red[wave + 4][lane];
        acc[0] += other[0]; acc[1] += other[1];
        acc[2] += other[2]; acc[3] += other[3];
        // denominator sits in d-row 8 = (g=2, reg 0), same column i
        const float den = __shfl(acc[0], il + 32);
        if (g < 2) {
            const float inv = 1.0f / den;
            float4 o;
            o.x = acc[0] * inv;
            o.y = acc[1] * inv;
            o.z = acc[2] * inv;
            o.w = acc[3] * inv;
            *(float4*)(out + ((size_t)b * HW + i) * 64 + h * 8 + g * 4) = o;
        }
    }
}

extern "C" void kernel_launch(void* const* d_in, const int* in_sizes, int n_in,
                              void* d_out, int out_size, void* d_ws, size_t ws_size,
                              hipStream_t stream) {
    const float* x    = (const float*)d_in[0];
    const float* y    = (const float*)d_in[1];
    const float* Wq   = (const float*)d_in[2];
    const float* bq   = (const float*)d_in[3];
    const float* Wkv  = (const float*)d_in[4];
    const float* bkv  = (const float*)d_in[5];
    const float* temp = (const float*)d_in[6];
    float* out = (float*)d_out;

    const size_t NQK = (size_t)NB * NH * HW * HD;   // 524288
    short* Qb  = (short*)d_ws;                       // 1 MB
    short* Kb  = Qb + NQK;                           // 1 MB
    short* VTp = Kb + NQK;                           // 1.125 MB

    proj_kernel<<<2 * (NB * HW) / 16, 256, 0, stream>>>(x, y, Wq, bq, Wkv, bkv,
                                                        temp, Qb, Kb, VTp);
    attn_kernel<<<NB * NH * (HW / 64), 512, 0, stream>>>(Qb, Kb, VTp, out);
}